// Round 9
// baseline (418.046 us; speedup 1.0000x reference)
//
#include <hip/hip_runtime.h>

#define N_OP   50000
#define N_MAC  2000
#define IN_OP  64
#define IN_MAC 32
#define OUT    128
#define HEADS  4
#define DK     32
#define ATT_DIM 65
#define E_SEQ  150000
#define E_OM   300000
#define E_MO   300000
#define TOT_E  (E_SEQ + E_MO + E_OM)
#define EPS    1e-6f
#define LN_EPS 1e-5f

#define ZROWS 100                 // z-GEMM LDS tile rows
#define GA2 (N_OP / ZROWS)        // 500 op z tiles
#define GB2 (N_MAC / ZROWS)       // 20 mac z tiles
#define GC 256                    // op projections: 1024 waves
#define GD 16                     // mac projections: 64 waves
#define CNT_B   ((TOT_E + 255) / 256)

#define AB_SEQ  ((N_OP + 255) / 256)
#define AB_MO   ((N_OP + 255) / 256)
#define AB_OM   ((N_MAC + 255) / 256)

typedef unsigned short ushort_t;
typedef unsigned int   uint_t;

__device__ __forceinline__ ushort_t f32_to_bf16_rtne(float f) {
    uint_t u = __float_as_uint(f);
    u += 0x7FFFu + ((u >> 16) & 1u);
    return (ushort_t)(u >> 16);
}

// ---------------------------------------------------------------------------
// Prep: block 0 folds attention through W (U = att o W, c = att o b);
// blocks >= 1 zero the count/ctr arrays.
// U_op row j = pr*4+hd: pr0=seq_src, pr1=seq_dst, pr2=om_src, pr3=mo_dst.
// U_mac row j: pr0=om_dst(att_om[32:64]), pr1=mo_src(att_mo[0:32]).
// ---------------------------------------------------------------------------
__global__ void k_prep(const float* __restrict__ W_op, const float* __restrict__ b_op,
                       const float* __restrict__ W_mac, const float* __restrict__ b_mac,
                       const float* __restrict__ att_seq, const float* __restrict__ att_om,
                       const float* __restrict__ att_mo,
                       float* __restrict__ U_op, float* __restrict__ c_op,
                       float* __restrict__ U_mac, float* __restrict__ c_mac,
                       int* __restrict__ zero_base) {
    const int t = threadIdx.x;
    if (blockIdx.x == 0) {
        for (int idx = t; idx < 16 * IN_OP; idx += 256) {
            const int j = idx >> 6, k = idx & 63;
            const int hd = j & 3, pr = j >> 2;
            const float* att = (pr <= 1) ? att_seq : (pr == 2 ? att_om : att_mo);
            const int off = (pr == 1 || pr == 3) ? 32 : 0;
            float s = 0.f;
            for (int l = 0; l < 32; ++l)
                s += att[hd * ATT_DIM + off + l] * W_op[(hd * 32 + l) * IN_OP + k];
            U_op[idx] = s;
        }
        if (t < 16) {
            const int hd = t & 3, pr = t >> 2;
            const float* att = (pr <= 1) ? att_seq : (pr == 2 ? att_om : att_mo);
            const int off = (pr == 1 || pr == 3) ? 32 : 0;
            float s = 0.f;
            for (int l = 0; l < 32; ++l) s += att[hd * ATT_DIM + off + l] * b_op[hd * 32 + l];
            c_op[t] = s;
        }
        for (int idx = t; idx < 8 * IN_MAC; idx += 256) {
            const int j = idx >> 5, k = idx & 31;
            const int hd = j & 3, pr = j >> 2;
            const float* att = (pr == 0) ? att_om : att_mo;
            const int off = (pr == 0) ? 32 : 0;
            float s = 0.f;
            for (int l = 0; l < 32; ++l)
                s += att[hd * ATT_DIM + off + l] * W_mac[(hd * 32 + l) * IN_MAC + k];
            U_mac[idx] = s;
        }
        if (t < 8) {
            const int hd = t & 3, pr = t >> 2;
            const float* att = (pr == 0) ? att_om : att_mo;
            const int off = (pr == 0) ? 32 : 0;
            float s = 0.f;
            for (int l = 0; l < 32; ++l) s += att[hd * ATT_DIM + off + l] * b_mac[hd * 32 + l];
            c_mac[t] = s;
        }
    } else {
        const int n = 2 * N_OP + N_MAC + 4;
        for (int i = (blockIdx.x - 1) * 256 + t; i < n; i += 63 * 256)
            zero_base[i] = 0;
    }
}

// ---------------------------------------------------------------------------
// GEMM kernel. z-GEMM regions use LDS-broadcast: 100-row h tile staged in LDS
// (coalesced), then each wave reads rows via UNIFORM ds_read_b128 (same-addr
// broadcast = conflict-free, no s_load latency chain). Wave owns a column
// half; its W column lives in float4 wv[16] (64 VGPR; cap 128 via bounds).
// Projections (C/D) keep the R8 wave-uniform form.
// ---------------------------------------------------------------------------
__global__ void __launch_bounds__(256, 4) k_gemm(
    const float* __restrict__ h_op, const float* __restrict__ W_op, const float* __restrict__ b_op,
    const float* __restrict__ h_mac, const float* __restrict__ W_mac, const float* __restrict__ b_mac,
    const float* __restrict__ U_op, const float* __restrict__ c_op,
    const float* __restrict__ U_mac, const float* __restrict__ c_mac,
    float* __restrict__ z_op, ushort_t* __restrict__ zb_op,
    float* __restrict__ z_mac, ushort_t* __restrict__ zb_mac,
    float* __restrict__ p_op, float* __restrict__ p_mac) {
    const int bid = blockIdx.x;
    const int t = threadIdx.x;
    const int w = t >> 6, lane = t & 63;
    __shared__ float hS[ZROWS * IN_OP];   // 25.6 KB

    if (bid < GA2) {
        // ---- [A] op z: 100-row tile; wave (w&1)=col half, (w>>1)=row parity ----
        const int row0 = bid * ZROWS;
        const int c = (w & 1) * 64 + lane;
        float4 wv[16];
        const float4* Wp = reinterpret_cast<const float4*>(W_op + (size_t)c * IN_OP);
#pragma unroll
        for (int k = 0; k < 16; ++k) wv[k] = Wp[k];
        const float bias = b_op[c];
        const float4* hg = reinterpret_cast<const float4*>(h_op + (size_t)row0 * IN_OP);
        float4* hs4 = reinterpret_cast<float4*>(hS);
        for (int i = t; i < ZROWS * IN_OP / 4; i += 256) hs4[i] = hg[i];
        __syncthreads();
        for (int r = (w >> 1); r < ZROWS; r += 2) {
            const float4* hv = reinterpret_cast<const float4*>(hS + r * IN_OP);
            float4 q = {0.f, 0.f, 0.f, 0.f};
#pragma unroll
            for (int k = 0; k < 16; ++k) {
                const float4 h4 = hv[k];           // uniform broadcast read
                q.x = fmaf(h4.x, wv[k].x, q.x);
                q.y = fmaf(h4.y, wv[k].y, q.y);
                q.z = fmaf(h4.z, wv[k].z, q.z);
                q.w = fmaf(h4.w, wv[k].w, q.w);
            }
            const float s = bias + ((q.x + q.y) + (q.z + q.w));
            const size_t o = (size_t)(row0 + r) * OUT + c;
            z_op[o] = s;
            zb_op[o] = f32_to_bf16_rtne(s);
        }
    } else if (bid < GA2 + GB2) {
        // ---- [B] mac z: same structure, K=32 ----
        const int row0 = (bid - GA2) * ZROWS;
        const int c = (w & 1) * 64 + lane;
        float4 wv[8];
        const float4* Wp = reinterpret_cast<const float4*>(W_mac + (size_t)c * IN_MAC);
#pragma unroll
        for (int k = 0; k < 8; ++k) wv[k] = Wp[k];
        const float bias = b_mac[c];
        const float4* hg = reinterpret_cast<const float4*>(h_mac + (size_t)row0 * IN_MAC);
        float4* hs4 = reinterpret_cast<float4*>(hS);
        for (int i = t; i < ZROWS * IN_MAC / 4; i += 256) hs4[i] = hg[i];
        __syncthreads();
        for (int r = (w >> 1); r < ZROWS; r += 2) {
            const float4* hv = reinterpret_cast<const float4*>(hS + r * IN_MAC);
            float4 q = {0.f, 0.f, 0.f, 0.f};
#pragma unroll
            for (int k = 0; k < 8; ++k) {
                const float4 h4 = hv[k];
                q.x = fmaf(h4.x, wv[k].x, q.x);
                q.y = fmaf(h4.y, wv[k].y, q.y);
                q.z = fmaf(h4.z, wv[k].z, q.z);
                q.w = fmaf(h4.w, wv[k].w, q.w);
            }
            const float s = bias + ((q.x + q.y) + (q.z + q.w));
            const size_t o = (size_t)(row0 + r) * OUT + c;
            z_mac[o] = s;
            zb_mac[o] = f32_to_bf16_rtne(s);
        }
    } else if (bid < GA2 + GB2 + GC) {
        // ---- [C] op projections: lane = (kg,j); k split 4 ways, shfl reduce ----
        const int wg = (bid - GA2 - GB2) * 4 + w;  // 0..1023
        const int j = lane & 15, kg = lane >> 4;
        float4 u4[4];
        const float4* Up = reinterpret_cast<const float4*>(U_op + j * IN_OP + kg * 16);
#pragma unroll
        for (int i = 0; i < 4; ++i) u4[i] = Up[i];
        const float cj = c_op[j];
        for (int r = wg * 2; r < N_OP; r += 1024 * 2) {
            const int row0 = __builtin_amdgcn_readfirstlane(r);
            const float* h0 = h_op + (size_t)row0 * IN_OP + kg * 16;
            const float* h1 = h0 + IN_OP;
            float4 q0 = {0.f, 0.f, 0.f, 0.f}, q1 = {0.f, 0.f, 0.f, 0.f};
#pragma unroll
            for (int i = 0; i < 4; ++i) {
                const float4 ui = u4[i];
                q0.x = fmaf(h0[4 * i + 0], ui.x, q0.x);
                q0.y = fmaf(h0[4 * i + 1], ui.y, q0.y);
                q0.z = fmaf(h0[4 * i + 2], ui.z, q0.z);
                q0.w = fmaf(h0[4 * i + 3], ui.w, q0.w);
                q1.x = fmaf(h1[4 * i + 0], ui.x, q1.x);
                q1.y = fmaf(h1[4 * i + 1], ui.y, q1.y);
                q1.z = fmaf(h1[4 * i + 2], ui.z, q1.z);
                q1.w = fmaf(h1[4 * i + 3], ui.w, q1.w);
            }
            float v0 = (q0.x + q0.y) + (q0.z + q0.w);
            float v1 = (q1.x + q1.y) + (q1.z + q1.w);
            v0 += __shfl_xor(v0, 16); v0 += __shfl_xor(v0, 32);
            v1 += __shfl_xor(v1, 16); v1 += __shfl_xor(v1, 32);
            if (kg == 0) {
                p_op[(size_t)row0 * 16 + j] = cj + v0;
                p_op[(size_t)(row0 + 1) * 16 + j] = cj + v1;
            }
        }
    } else {
        // ---- [D] mac projections: lane = (kg,j), 8 k-groups of 4 ----
        const int wg = (bid - GA2 - GB2 - GC) * 4 + w;  // 0..63
        const int j = lane & 7, kg = lane >> 3;
        const float4 u4 = *reinterpret_cast<const float4*>(U_mac + j * IN_MAC + kg * 4);
        const float cj = c_mac[j];
        for (int r = wg * 2; r < N_MAC; r += 64 * 2) {
            const int row0 = __builtin_amdgcn_readfirstlane(r);
            const float* h0 = h_mac + (size_t)row0 * IN_MAC + kg * 4;
            const float* h1 = h0 + IN_MAC;
            float v0 = fmaf(h0[0], u4.x, fmaf(h0[1], u4.y, fmaf(h0[2], u4.z, h0[3] * u4.w)));
            float v1 = fmaf(h1[0], u4.x, fmaf(h1[1], u4.y, fmaf(h1[2], u4.z, h1[3] * u4.w)));
            v0 += __shfl_xor(v0, 8); v0 += __shfl_xor(v0, 16); v0 += __shfl_xor(v0, 32);
            v1 += __shfl_xor(v1, 8); v1 += __shfl_xor(v1, 16); v1 += __shfl_xor(v1, 32);
            if (kg == 0) {
                p_mac[(size_t)row0 * 8 + j] = cj + v0;
                p_mac[(size_t)(row0 + 1) * 8 + j] = cj + v1;
            }
        }
    }
}

// ---------------------------------------------------------------------------
// Degree histograms.
// ---------------------------------------------------------------------------
__global__ void k_histo(const int* __restrict__ seq_dst, const int* __restrict__ mo_dst,
                        const int* __restrict__ om_dst,
                        int* __restrict__ cnt_seq, int* __restrict__ cnt_mo,
                        int* __restrict__ cnt_om) {
    const int ge = blockIdx.x * 256 + threadIdx.x;
    if (ge < E_SEQ) atomicAdd(&cnt_seq[seq_dst[ge]], 1);
    else if (ge < E_SEQ + E_MO) atomicAdd(&cnt_mo[mo_dst[ge - E_SEQ]], 1);
    else if (ge < TOT_E) atomicAdd(&cnt_om[om_dst[ge - E_SEQ - E_MO]], 1);
}

// ---------------------------------------------------------------------------
// Range allocation: per-wave scan of counts + one atomicAdd per wave.
// ---------------------------------------------------------------------------
__global__ void k_alloc(const int* __restrict__ cnt_seq, int* __restrict__ sta_seq, int* __restrict__ off_seq,
                        const int* __restrict__ cnt_mo,  int* __restrict__ sta_mo,  int* __restrict__ off_mo,
                        const int* __restrict__ cnt_om,  int* __restrict__ sta_om,  int* __restrict__ off_om,
                        int* __restrict__ ctr) {
    const int b = blockIdx.x, t = threadIdx.x;
    const int* cnt; int* sta; int* off; int n, g, lb;
    if (b < AB_SEQ)             { cnt = cnt_seq; sta = sta_seq; off = off_seq; n = N_OP;  g = 0; lb = b; }
    else if (b < AB_SEQ + AB_MO){ cnt = cnt_mo;  sta = sta_mo;  off = off_mo;  n = N_OP;  g = 1; lb = b - AB_SEQ; }
    else                        { cnt = cnt_om;  sta = sta_om;  off = off_om;  n = N_MAC; g = 2; lb = b - AB_SEQ - AB_MO; }
    const int d = lb * 256 + t;
    const int lane = t & 63;
    const int v = (d < n) ? cnt[d] : 0;
    int x = v;
#pragma unroll
    for (int m = 1; m < 64; m <<= 1) {
        int y = __shfl_up(x, m);
        if (lane >= m) x += y;
    }
    int base = 0;
    if (lane == 63) base = atomicAdd(&ctr[g], x);
    base = __shfl(base, 63);
    if (d < n) {
        const int s = base + x - v;
        sta[d] = s;
        off[d] = s;
    }
}

// ---------------------------------------------------------------------------
// Fill + alpha (all 3 graphs), written in bucket order. Alpha stored as
// 4x bf16 packed in uint2 (8B/edge, was 16B).
// ---------------------------------------------------------------------------
__global__ void k_fill_alpha(
    const int* __restrict__ seq_src, const int* __restrict__ seq_dst, const float* __restrict__ feat_seq,
    const int* __restrict__ mo_src,  const int* __restrict__ mo_dst,  const float* __restrict__ feat_mo,
    const int* __restrict__ om_src,  const int* __restrict__ om_dst,  const float* __restrict__ feat_om,
    const float* __restrict__ p_op, const float* __restrict__ p_mac,
    const float* __restrict__ att_seq, const float* __restrict__ att_mo, const float* __restrict__ att_om,
    int* __restrict__ off_seq, int* __restrict__ off_mo, int* __restrict__ off_om,
    ushort_t* __restrict__ al_seq, ushort_t* __restrict__ al_mo, ushort_t* __restrict__ al_om,
    int* __restrict__ bs_seq, int* __restrict__ bs_mo, int* __restrict__ bs_om) {
    const int ge = blockIdx.x * 256 + threadIdx.x;
    if (ge >= TOT_E) return;
    int s, d, pos;
    float f;
    float4 as, ad, aw;
    int* bs; ushort_t* abkt;
    if (ge < E_SEQ) {
        const int e = ge;
        s = seq_src[e]; d = seq_dst[e]; f = feat_seq[e];
        as = *reinterpret_cast<const float4*>(p_op + (size_t)s * 16 + 0);
        ad = *reinterpret_cast<const float4*>(p_op + (size_t)d * 16 + 4);
        aw = make_float4(att_seq[64], att_seq[ATT_DIM + 64], att_seq[2 * ATT_DIM + 64], att_seq[3 * ATT_DIM + 64]);
        pos = atomicAdd(&off_seq[d], 1);
        abkt = al_seq; bs = bs_seq;
    } else if (ge < E_SEQ + E_MO) {
        const int e = ge - E_SEQ;
        s = mo_src[e]; d = mo_dst[e]; f = feat_mo[e];
        as = *reinterpret_cast<const float4*>(p_mac + (size_t)s * 8 + 4);
        ad = *reinterpret_cast<const float4*>(p_op + (size_t)d * 16 + 12);
        aw = make_float4(att_mo[64], att_mo[ATT_DIM + 64], att_mo[2 * ATT_DIM + 64], att_mo[3 * ATT_DIM + 64]);
        pos = atomicAdd(&off_mo[d], 1);
        abkt = al_mo; bs = bs_mo;
    } else {
        const int e = ge - E_SEQ - E_MO;
        s = om_src[e]; d = om_dst[e]; f = feat_om[e];
        as = *reinterpret_cast<const float4*>(p_op + (size_t)s * 16 + 8);
        ad = *reinterpret_cast<const float4*>(p_mac + (size_t)d * 8 + 0);
        aw = make_float4(att_om[64], att_om[ATT_DIM + 64], att_om[2 * ATT_DIM + 64], att_om[3 * ATT_DIM + 64]);
        pos = atomicAdd(&off_om[d], 1);
        abkt = al_om; bs = bs_om;
    }
    const float sc[4] = {as.x + ad.x + f * aw.x, as.y + ad.y + f * aw.y,
                         as.z + ad.z + f * aw.z, as.w + ad.w + f * aw.w};
    uint_t b16[4];
#pragma unroll
    for (int hh = 0; hh < 4; ++hh) {
        float v = sc[hh];
        v = (v >= 0.f) ? v : 0.2f * v;
        v = fminf(fmaxf(v, -20.f), 20.f);
        b16[hh] = f32_to_bf16_rtne(expf(v));
    }
    uint2 pal;
    pal.x = b16[0] | (b16[1] << 16);
    pal.y = b16[2] | (b16[3] << 16);
    *reinterpret_cast<uint2*>(abkt + (size_t)pos * HEADS) = pal;
    bs[pos] = s;
}

// ---------------------------------------------------------------------------
// Gather. mac rows: one BLOCK per row. op rows: one WAVE per row.
// bf16 alpha (2B broadcast loads), bf16 z gathers, wave LN + ELU.
// ---------------------------------------------------------------------------
__device__ __forceinline__ void seg2(const int* __restrict__ bs, const ushort_t* __restrict__ al,
                                     const ushort_t* __restrict__ zb,
                                     int s0, int e0, int stride, int lane, int hd, int col2,
                                     float& num0, float& num1, float& den) {
    for (int base = s0; base < e0; base += stride) {
        int nn = e0 - base;
        if (nn > 64) nn = 64;
        int sidx = 0;
        if (base + lane < e0) sidx = bs[base + lane];
#pragma unroll 8
        for (int i = 0; i < nn; ++i) {
            const int s = __shfl(sidx, i);
            const float a = __uint_as_float(((uint_t)al[(size_t)(base + i) * HEADS + hd]) << 16);
            const uint_t zz = *reinterpret_cast<const uint_t*>(zb + (size_t)s * OUT + col2);
            num0 = fmaf(a, __uint_as_float(zz << 16), num0);
            num1 = fmaf(a, __uint_as_float(zz & 0xffff0000u), num1);
            den += a;
        }
    }
}

__device__ __forceinline__ float2 ln_elu2(float x0, float x1, int lane,
                                          const float* __restrict__ g,
                                          const float* __restrict__ bb, int col2) {
    float s = x0 + x1;
#pragma unroll
    for (int m = 32; m >= 1; m >>= 1) s += __shfl_xor(s, m);
    const float mu = s * (1.0f / OUT);
    const float dx0 = x0 - mu, dx1 = x1 - mu;
    float q = dx0 * dx0 + dx1 * dx1;
#pragma unroll
    for (int m = 32; m >= 1; m >>= 1) q += __shfl_xor(q, m);
    const float r = rsqrtf(q * (1.0f / OUT) + LN_EPS);
    const float2 g2 = *reinterpret_cast<const float2*>(g + col2);
    const float2 b2 = *reinterpret_cast<const float2*>(bb + col2);
    float y0 = dx0 * r * g2.x + b2.x;
    float y1 = dx1 * r * g2.y + b2.y;
    y0 = (y0 > 0.f) ? y0 : expm1f(y0);
    y1 = (y1 > 0.f) ? y1 : expm1f(y1);
    return make_float2(y0, y1);
}

__global__ void k_gather(
    const int* __restrict__ bs_seq, const ushort_t* __restrict__ al_seq,
    const int* __restrict__ sta_seq, const int* __restrict__ off_seq,
    const int* __restrict__ bs_mo, const ushort_t* __restrict__ al_mo,
    const int* __restrict__ sta_mo, const int* __restrict__ off_mo,
    const int* __restrict__ bs_om, const ushort_t* __restrict__ al_om,
    const int* __restrict__ sta_om, const int* __restrict__ off_om,
    const ushort_t* __restrict__ zb_op, const ushort_t* __restrict__ zb_mac,
    const float* __restrict__ z_op, const float* __restrict__ z_mac,
    const float* __restrict__ g_op, const float* __restrict__ b_op,
    const float* __restrict__ g_mac, const float* __restrict__ b_mac,
    float* __restrict__ out_op, float* __restrict__ out_mac) {
    const int bid = blockIdx.x;
    const int t = threadIdx.x;
    const int w = t >> 6, lane = t & 63;
    const int hd = lane >> 4;
    const int col2 = lane * 2;
    __shared__ float nsh[4][OUT];
    __shared__ float dsh[4][HEADS];

    if (bid < N_MAC) {
        const int d = bid;
        const int s0 = sta_om[d], e0 = off_om[d];
        float num0 = 0.f, num1 = 0.f, den = 0.f;
        seg2(bs_om, al_om, zb_op, s0 + w * 64, e0, 256, lane, hd, col2, num0, num1, den);
        nsh[w][col2] = num0;
        nsh[w][col2 + 1] = num1;
        if ((lane & 15) == 0) dsh[w][hd] = den;
        __syncthreads();
        if (w == 0) {
            const float n0 = nsh[0][col2] + nsh[1][col2] + nsh[2][col2] + nsh[3][col2];
            const float n1 = nsh[0][col2 + 1] + nsh[1][col2 + 1] + nsh[2][col2 + 1] + nsh[3][col2 + 1];
            const float dt = dsh[0][hd] + dsh[1][hd] + dsh[2][hd] + dsh[3][hd];
            const float inv = 1.0f / (dt + EPS);
            const float2 zr = *reinterpret_cast<const float2*>(z_mac + (size_t)d * OUT + col2);
            const float2 o2 = ln_elu2(n0 * inv + zr.x, n1 * inv + zr.y, lane, g_mac, b_mac, col2);
            *reinterpret_cast<float2*>(out_mac + (size_t)d * OUT + col2) = o2;
        }
    } else {
        const int d = (bid - N_MAC) * 4 + w;
        if (d >= N_OP) return;
        float acc0 = 0.f, acc1 = 0.f;
        {
            float num0 = 0.f, num1 = 0.f, den = 0.f;
            seg2(bs_seq, al_seq, zb_op, sta_seq[d], off_seq[d], 64, lane, hd, col2, num0, num1, den);
            const float inv = 1.0f / (den + EPS);
            acc0 = num0 * inv; acc1 = num1 * inv;
        }
        {
            float num0 = 0.f, num1 = 0.f, den = 0.f;
            seg2(bs_mo, al_mo, zb_mac, sta_mo[d], off_mo[d], 64, lane, hd, col2, num0, num1, den);
            const float inv = 1.0f / (den + EPS);
            acc0 += num0 * inv; acc1 += num1 * inv;
        }
        const float2 zr = *reinterpret_cast<const float2*>(z_op + (size_t)d * OUT + col2);
        const float2 o2 = ln_elu2(acc0 + zr.x, acc1 + zr.y, lane, g_op, b_op, col2);
        *reinterpret_cast<float2*>(out_op + (size_t)d * OUT + col2) = o2;
    }
}

extern "C" void kernel_launch(void* const* d_in, const int* in_sizes, int n_in,
                              void* d_out, int out_size, void* d_ws, size_t ws_size,
                              hipStream_t stream) {
    const float* h_op      = (const float*)d_in[0];
    const float* h_mac     = (const float*)d_in[1];
    const int*   seq_src   = (const int*)d_in[2];
    const int*   seq_dst   = (const int*)d_in[3];
    const int*   om_src    = (const int*)d_in[4];
    const int*   om_dst    = (const int*)d_in[5];
    const int*   mo_src    = (const int*)d_in[6];
    const int*   mo_dst    = (const int*)d_in[7];
    const float* feat_seq  = (const float*)d_in[8];
    const float* feat_om   = (const float*)d_in[9];
    const float* feat_mo   = (const float*)d_in[10];
    const float* W_op_w    = (const float*)d_in[11];
    const float* W_op_b    = (const float*)d_in[12];
    const float* W_mac_w   = (const float*)d_in[13];
    const float* W_mac_b   = (const float*)d_in[14];
    const float* att_seq   = (const float*)d_in[15];
    const float* att_om    = (const float*)d_in[16];
    const float* att_mo    = (const float*)d_in[17];
    const float* ln_op_g   = (const float*)d_in[18];
    const float* ln_op_b   = (const float*)d_in[19];
    const float* ln_mac_g  = (const float*)d_in[20];
    const float* ln_mac_b  = (const float*)d_in[21];

    float* p = (float*)d_ws;
    float* z_op   = p; p += (size_t)N_OP * OUT;
    float* z_mac  = p; p += (size_t)N_MAC * OUT;
    float* p_op   = p; p += (size_t)N_OP * 16;
    float* p_mac  = p; p += (size_t)N_MAC * 8;
    ushort_t* al_seq = (ushort_t*)p; p += (size_t)E_SEQ * HEADS / 2;
    ushort_t* al_mo  = (ushort_t*)p; p += (size_t)E_MO * HEADS / 2;
    ushort_t* al_om  = (ushort_t*)p; p += (size_t)E_OM * HEADS / 2;
    float* U_op   = p; p += 16 * IN_OP;
    float* c_op   = p; p += 16;
    float* U_mac  = p; p += 8 * IN_MAC;
    float* c_mac  = p; p += 16;
    ushort_t* zb_op  = (ushort_t*)p; p += (size_t)N_OP * OUT / 2;
    ushort_t* zb_mac = (ushort_t*)p; p += (size_t)N_MAC * OUT / 2;
    int* q = (int*)p;
    int* cnt_seq = q; q += N_OP;    // cnt_* + ctr contiguous, zeroed in k_prep
    int* cnt_mo  = q; q += N_OP;
    int* cnt_om  = q; q += N_MAC;
    int* ctr     = q; q += 4;
    int* sta_seq = q; q += N_OP;
    int* sta_mo  = q; q += N_OP;
    int* sta_om  = q; q += N_MAC;
    int* off_seq = q; q += N_OP;
    int* off_mo  = q; q += N_OP;
    int* off_om  = q; q += N_MAC;
    int* bs_seq  = q; q += E_SEQ;
    int* bs_mo   = q; q += E_MO;
    int* bs_om   = q; q += E_OM;

    float* out_op  = (float*)d_out;
    float* out_mac = (float*)d_out + (size_t)N_OP * OUT;

    k_prep<<<64, 256, 0, stream>>>(W_op_w, W_op_b, W_mac_w, W_mac_b,
                                   att_seq, att_om, att_mo,
                                   U_op, c_op, U_mac, c_mac, cnt_seq);

    k_gemm<<<GA2 + GB2 + GC + GD, 256, 0, stream>>>(
        h_op, W_op_w, W_op_b, h_mac, W_mac_w, W_mac_b,
        U_op, c_op, U_mac, c_mac,
        z_op, zb_op, z_mac, zb_mac, p_op, p_mac);

    k_histo<<<CNT_B, 256, 0, stream>>>(seq_dst, mo_dst, om_dst, cnt_seq, cnt_mo, cnt_om);

    k_alloc<<<AB_SEQ + AB_MO + AB_OM, 256, 0, stream>>>(
        cnt_seq, sta_seq, off_seq, cnt_mo, sta_mo, off_mo, cnt_om, sta_om, off_om, ctr);

    k_fill_alpha<<<CNT_B, 256, 0, stream>>>(
        seq_src, seq_dst, feat_seq, mo_src, mo_dst, feat_mo, om_src, om_dst, feat_om,
        p_op, p_mac, att_seq, att_mo, att_om,
        off_seq, off_mo, off_om,
        al_seq, al_mo, al_om, bs_seq, bs_mo, bs_om);

    k_gather<<<N_MAC + (N_OP + 3) / 4, 256, 0, stream>>>(
        bs_seq, al_seq, sta_seq, off_seq,
        bs_mo, al_mo, sta_mo, off_mo,
        bs_om, al_om, sta_om, off_om,
        zb_op, zb_mac, z_op, z_mac,
        ln_op_g, ln_op_b, ln_mac_g, ln_mac_b,
        out_op, out_mac);
}

// Round 10
// 236.480 us; speedup vs baseline: 1.7678x; 1.7678x over previous
//
#include <hip/hip_runtime.h>

#define N_OP   50000
#define N_MAC  2000
#define IN_OP  64
#define IN_MAC 32
#define OUT    128
#define HEADS  4
#define DK     32
#define ATT_DIM 65
#define E_SEQ  150000
#define E_OM   300000
#define E_MO   300000
#define TOT_E  (E_SEQ + E_MO + E_OM)
#define EPS    1e-6f
#define LN_EPS 1e-5f

#define TILES_OP  (N_OP / 16)            // 3125
#define TILES_MAC (N_MAC / 16)           // 125
#define GBA ((TILES_OP + 3) / 4)         // 782 blocks, 1 tile per wave
#define GBB ((TILES_MAC + 3) / 4)        // 32 blocks
#define CNT_B   ((TOT_E + 255) / 256)

#define AB_SEQ  ((N_OP + 255) / 256)
#define AB_MO   ((N_OP + 255) / 256)
#define AB_OM   ((N_MAC + 255) / 256)

typedef unsigned short ushort_t;
typedef unsigned int   uint_t;
typedef __attribute__((ext_vector_type(8))) short bf16x8;
typedef __attribute__((ext_vector_type(4))) float f32x4;

__device__ __forceinline__ ushort_t f32_to_bf16_rtne(float f) {
    uint_t u = __float_as_uint(f);
    u += 0x7FFFu + ((u >> 16) & 1u);
    return (ushort_t)(u >> 16);
}

// ---------------------------------------------------------------------------
// Prep. Block 0: fold attention through W (U = att o W, c = att o b) writing
// both f32 and bf16 copies; convert W -> bf16. Blocks 1..63: zero cnt/ctr.
// Blocks 64..255: convert h -> bf16.
// U_op row j = pr*4+hd: pr0=seq_src, pr1=seq_dst, pr2=om_src, pr3=mo_dst.
// U_mac row j: pr0=om_dst(att_om[32:64]), pr1=mo_src(att_mo[0:32]); rows 8..15 = 0.
// ---------------------------------------------------------------------------
__global__ void k_prep(const float* __restrict__ W_op, const float* __restrict__ b_op,
                       const float* __restrict__ W_mac, const float* __restrict__ b_mac,
                       const float* __restrict__ att_seq, const float* __restrict__ att_om,
                       const float* __restrict__ att_mo,
                       const float* __restrict__ h_op, const float* __restrict__ h_mac,
                       float* __restrict__ c_op, float* __restrict__ c_mac,
                       ushort_t* __restrict__ Wb_op, ushort_t* __restrict__ Wb_mac,
                       ushort_t* __restrict__ Ub_op, ushort_t* __restrict__ Ub_mac,
                       ushort_t* __restrict__ hb_op, ushort_t* __restrict__ hb_mac,
                       int* __restrict__ zero_base) {
    const int t = threadIdx.x;
    const int b = blockIdx.x;
    if (b == 0) {
        for (int idx = t; idx < 16 * IN_OP; idx += 256) {
            const int j = idx >> 6, k = idx & 63;
            const int hd = j & 3, pr = j >> 2;
            const float* att = (pr <= 1) ? att_seq : (pr == 2 ? att_om : att_mo);
            const int off = (pr == 1 || pr == 3) ? 32 : 0;
            float s = 0.f;
            for (int l = 0; l < 32; ++l)
                s += att[hd * ATT_DIM + off + l] * W_op[(hd * 32 + l) * IN_OP + k];
            Ub_op[idx] = f32_to_bf16_rtne(s);
        }
        if (t < 16) {
            const int hd = t & 3, pr = t >> 2;
            const float* att = (pr <= 1) ? att_seq : (pr == 2 ? att_om : att_mo);
            const int off = (pr == 1 || pr == 3) ? 32 : 0;
            float s = 0.f;
            for (int l = 0; l < 32; ++l) s += att[hd * ATT_DIM + off + l] * b_op[hd * 32 + l];
            c_op[t] = s;
        }
        for (int idx = t; idx < 8 * IN_MAC; idx += 256) {
            const int j = idx >> 5, k = idx & 31;
            const int hd = j & 3, pr = j >> 2;
            const float* att = (pr == 0) ? att_om : att_mo;
            const int off = (pr == 0) ? 32 : 0;
            float s = 0.f;
            for (int l = 0; l < 32; ++l)
                s += att[hd * ATT_DIM + off + l] * W_mac[(hd * 32 + l) * IN_MAC + k];
            Ub_mac[idx] = f32_to_bf16_rtne(s);
        }
        for (int idx = 8 * IN_MAC + t; idx < 16 * IN_MAC; idx += 256) Ub_mac[idx] = 0;
        if (t < 8) {
            const int hd = t & 3, pr = t >> 2;
            const float* att = (pr == 0) ? att_om : att_mo;
            const int off = (pr == 0) ? 32 : 0;
            float s = 0.f;
            for (int l = 0; l < 32; ++l) s += att[hd * ATT_DIM + off + l] * b_mac[hd * 32 + l];
            c_mac[t] = s;
        }
        for (int idx = t; idx < OUT * IN_OP; idx += 256) Wb_op[idx] = f32_to_bf16_rtne(W_op[idx]);
        for (int idx = t; idx < OUT * IN_MAC; idx += 256) Wb_mac[idx] = f32_to_bf16_rtne(W_mac[idx]);
    } else if (b < 64) {
        const int n = 2 * N_OP + N_MAC + 4;
        for (int i = (b - 1) * 256 + t; i < n; i += 63 * 256)
            zero_base[i] = 0;
    } else {
        const int base = (b - 64) * 256 + t;
        const int stride = 192 * 256;
        for (int i = base; i < N_OP * IN_OP; i += stride)
            hb_op[i] = f32_to_bf16_rtne(h_op[i]);
        for (int i = base; i < N_MAC * IN_MAC; i += stride)
            hb_mac[i] = f32_to_bf16_rtne(h_mac[i]);
    }
}

// ---------------------------------------------------------------------------
// MFMA GEMM. One wave = one 16-row tile. Fragments are direct 16B global
// loads (no LDS, no big reg arrays):
//   A (h):  lane l -> row = row0+(l&15), k = (l>>4)*8 + j  (+32 for kstep 1)
//   B (W):  lane l -> col = ct*16+(l&15), same k mapping   (B[k][n] = W[n][k])
//   C/D:    col = lane&15, row = (lane>>4)*4 + reg   [verified m89]
// z tiles (8 col-tiles) + fused projection tile (U as a 9th B-matrix).
// ---------------------------------------------------------------------------
__global__ void k_gemm(
    const ushort_t* __restrict__ hb_op, const ushort_t* __restrict__ Wb_op,
    const float* __restrict__ b_op,
    const ushort_t* __restrict__ hb_mac, const ushort_t* __restrict__ Wb_mac,
    const float* __restrict__ b_mac,
    const ushort_t* __restrict__ Ub_op, const float* __restrict__ c_op,
    const ushort_t* __restrict__ Ub_mac, const float* __restrict__ c_mac,
    float* __restrict__ z_op, ushort_t* __restrict__ zb_op,
    float* __restrict__ z_mac, ushort_t* __restrict__ zb_mac,
    float* __restrict__ p_op, float* __restrict__ p_mac) {
    const int bid = blockIdx.x;
    const int t = threadIdx.x;
    const int w = t >> 6, l = t & 63;
    const int li = l & 15, lg = l >> 4;

    if (bid < GBA) {
        const int tile = bid * 4 + w;
        if (tile >= TILES_OP) return;
        const int row0 = tile * 16;
        const bf16x8 a0 = *reinterpret_cast<const bf16x8*>(hb_op + (size_t)(row0 + li) * IN_OP + lg * 8);
        const bf16x8 a1 = *reinterpret_cast<const bf16x8*>(hb_op + (size_t)(row0 + li) * IN_OP + lg * 8 + 32);
        const int orow = row0 + lg * 4;
#pragma unroll
        for (int ct = 0; ct < 8; ++ct) {
            const int col = ct * 16 + li;
            const bf16x8 b0 = *reinterpret_cast<const bf16x8*>(Wb_op + (size_t)col * IN_OP + lg * 8);
            const bf16x8 b1 = *reinterpret_cast<const bf16x8*>(Wb_op + (size_t)col * IN_OP + lg * 8 + 32);
            f32x4 acc = {0.f, 0.f, 0.f, 0.f};
            acc = __builtin_amdgcn_mfma_f32_16x16x32_bf16(a0, b0, acc, 0, 0, 0);
            acc = __builtin_amdgcn_mfma_f32_16x16x32_bf16(a1, b1, acc, 0, 0, 0);
            const float bias = b_op[col];
#pragma unroll
            for (int r = 0; r < 4; ++r) {
                const float s = acc[r] + bias;
                const size_t o = (size_t)(orow + r) * OUT + col;
                z_op[o] = s;
                zb_op[o] = f32_to_bf16_rtne(s);
            }
        }
        {   // projection tile: p_op[row][j], j = lane&15
            const bf16x8 u0 = *reinterpret_cast<const bf16x8*>(Ub_op + (size_t)li * IN_OP + lg * 8);
            const bf16x8 u1 = *reinterpret_cast<const bf16x8*>(Ub_op + (size_t)li * IN_OP + lg * 8 + 32);
            f32x4 acc = {0.f, 0.f, 0.f, 0.f};
            acc = __builtin_amdgcn_mfma_f32_16x16x32_bf16(a0, u0, acc, 0, 0, 0);
            acc = __builtin_amdgcn_mfma_f32_16x16x32_bf16(a1, u1, acc, 0, 0, 0);
            const float cj = c_op[li];
#pragma unroll
            for (int r = 0; r < 4; ++r)
                p_op[(size_t)(orow + r) * 16 + li] = acc[r] + cj;
        }
    } else {
        const int tile = (bid - GBA) * 4 + w;
        if (tile >= TILES_MAC) return;
        const int row0 = tile * 16;
        const bf16x8 a0 = *reinterpret_cast<const bf16x8*>(hb_mac + (size_t)(row0 + li) * IN_MAC + lg * 8);
        const int orow = row0 + lg * 4;
#pragma unroll
        for (int ct = 0; ct < 8; ++ct) {
            const int col = ct * 16 + li;
            const bf16x8 b0 = *reinterpret_cast<const bf16x8*>(Wb_mac + (size_t)col * IN_MAC + lg * 8);
            f32x4 acc = {0.f, 0.f, 0.f, 0.f};
            acc = __builtin_amdgcn_mfma_f32_16x16x32_bf16(a0, b0, acc, 0, 0, 0);
            const float bias = b_mac[col];
#pragma unroll
            for (int r = 0; r < 4; ++r) {
                const float s = acc[r] + bias;
                const size_t o = (size_t)(orow + r) * OUT + col;
                z_mac[o] = s;
                zb_mac[o] = f32_to_bf16_rtne(s);
            }
        }
        {
            const bf16x8 u0 = *reinterpret_cast<const bf16x8*>(Ub_mac + (size_t)li * IN_MAC + lg * 8);
            f32x4 acc = {0.f, 0.f, 0.f, 0.f};
            acc = __builtin_amdgcn_mfma_f32_16x16x32_bf16(a0, u0, acc, 0, 0, 0);
            if (li < 8) {
                const float cj = c_mac[li];
#pragma unroll
                for (int r = 0; r < 4; ++r)
                    p_mac[(size_t)(orow + r) * 8 + li] = acc[r] + cj;
            }
        }
    }
}

// ---------------------------------------------------------------------------
// Degree histograms.
// ---------------------------------------------------------------------------
__global__ void k_histo(const int* __restrict__ seq_dst, const int* __restrict__ mo_dst,
                        const int* __restrict__ om_dst,
                        int* __restrict__ cnt_seq, int* __restrict__ cnt_mo,
                        int* __restrict__ cnt_om) {
    const int ge = blockIdx.x * 256 + threadIdx.x;
    if (ge < E_SEQ) atomicAdd(&cnt_seq[seq_dst[ge]], 1);
    else if (ge < E_SEQ + E_MO) atomicAdd(&cnt_mo[mo_dst[ge - E_SEQ]], 1);
    else if (ge < TOT_E) atomicAdd(&cnt_om[om_dst[ge - E_SEQ - E_MO]], 1);
}

// ---------------------------------------------------------------------------
// Range allocation: per-wave scan of counts + one atomicAdd per wave.
// ---------------------------------------------------------------------------
__global__ void k_alloc(const int* __restrict__ cnt_seq, int* __restrict__ sta_seq, int* __restrict__ off_seq,
                        const int* __restrict__ cnt_mo,  int* __restrict__ sta_mo,  int* __restrict__ off_mo,
                        const int* __restrict__ cnt_om,  int* __restrict__ sta_om,  int* __restrict__ off_om,
                        int* __restrict__ ctr) {
    const int b = blockIdx.x, t = threadIdx.x;
    const int* cnt; int* sta; int* off; int n, g, lb;
    if (b < AB_SEQ)             { cnt = cnt_seq; sta = sta_seq; off = off_seq; n = N_OP;  g = 0; lb = b; }
    else if (b < AB_SEQ + AB_MO){ cnt = cnt_mo;  sta = sta_mo;  off = off_mo;  n = N_OP;  g = 1; lb = b - AB_SEQ; }
    else                        { cnt = cnt_om;  sta = sta_om;  off = off_om;  n = N_MAC; g = 2; lb = b - AB_SEQ - AB_MO; }
    const int d = lb * 256 + t;
    const int lane = t & 63;
    const int v = (d < n) ? cnt[d] : 0;
    int x = v;
#pragma unroll
    for (int m = 1; m < 64; m <<= 1) {
        int y = __shfl_up(x, m);
        if (lane >= m) x += y;
    }
    int base = 0;
    if (lane == 63) base = atomicAdd(&ctr[g], x);
    base = __shfl(base, 63);
    if (d < n) {
        const int s = base + x - v;
        sta[d] = s;
        off[d] = s;
    }
}

// ---------------------------------------------------------------------------
// Fill + alpha (all 3 graphs), bucket order; alpha packed bf16 (8B/edge).
// ---------------------------------------------------------------------------
__global__ void k_fill_alpha(
    const int* __restrict__ seq_src, const int* __restrict__ seq_dst, const float* __restrict__ feat_seq,
    const int* __restrict__ mo_src,  const int* __restrict__ mo_dst,  const float* __restrict__ feat_mo,
    const int* __restrict__ om_src,  const int* __restrict__ om_dst,  const float* __restrict__ feat_om,
    const float* __restrict__ p_op, const float* __restrict__ p_mac,
    const float* __restrict__ att_seq, const float* __restrict__ att_mo, const float* __restrict__ att_om,
    int* __restrict__ off_seq, int* __restrict__ off_mo, int* __restrict__ off_om,
    ushort_t* __restrict__ al_seq, ushort_t* __restrict__ al_mo, ushort_t* __restrict__ al_om,
    int* __restrict__ bs_seq, int* __restrict__ bs_mo, int* __restrict__ bs_om) {
    const int ge = blockIdx.x * 256 + threadIdx.x;
    if (ge >= TOT_E) return;
    int s, d, pos;
    float f;
    float4 as, ad, aw;
    int* bs; ushort_t* abkt;
    if (ge < E_SEQ) {
        const int e = ge;
        s = seq_src[e]; d = seq_dst[e]; f = feat_seq[e];
        as = *reinterpret_cast<const float4*>(p_op + (size_t)s * 16 + 0);
        ad = *reinterpret_cast<const float4*>(p_op + (size_t)d * 16 + 4);
        aw = make_float4(att_seq[64], att_seq[ATT_DIM + 64], att_seq[2 * ATT_DIM + 64], att_seq[3 * ATT_DIM + 64]);
        pos = atomicAdd(&off_seq[d], 1);
        abkt = al_seq; bs = bs_seq;
    } else if (ge < E_SEQ + E_MO) {
        const int e = ge - E_SEQ;
        s = mo_src[e]; d = mo_dst[e]; f = feat_mo[e];
        as = *reinterpret_cast<const float4*>(p_mac + (size_t)s * 8 + 4);
        ad = *reinterpret_cast<const float4*>(p_op + (size_t)d * 16 + 12);
        aw = make_float4(att_mo[64], att_mo[ATT_DIM + 64], att_mo[2 * ATT_DIM + 64], att_mo[3 * ATT_DIM + 64]);
        pos = atomicAdd(&off_mo[d], 1);
        abkt = al_mo; bs = bs_mo;
    } else {
        const int e = ge - E_SEQ - E_MO;
        s = om_src[e]; d = om_dst[e]; f = feat_om[e];
        as = *reinterpret_cast<const float4*>(p_op + (size_t)s * 16 + 8);
        ad = *reinterpret_cast<const float4*>(p_mac + (size_t)d * 8 + 0);
        aw = make_float4(att_om[64], att_om[ATT_DIM + 64], att_om[2 * ATT_DIM + 64], att_om[3 * ATT_DIM + 64]);
        pos = atomicAdd(&off_om[d], 1);
        abkt = al_om; bs = bs_om;
    }
    const float sc[4] = {as.x + ad.x + f * aw.x, as.y + ad.y + f * aw.y,
                         as.z + ad.z + f * aw.z, as.w + ad.w + f * aw.w};
    uint_t b16[4];
#pragma unroll
    for (int hh = 0; hh < 4; ++hh) {
        float v = sc[hh];
        v = (v >= 0.f) ? v : 0.2f * v;
        v = fminf(fmaxf(v, -20.f), 20.f);
        b16[hh] = f32_to_bf16_rtne(expf(v));
    }
    uint2 pal;
    pal.x = b16[0] | (b16[1] << 16);
    pal.y = b16[2] | (b16[3] << 16);
    *reinterpret_cast<uint2*>(abkt + (size_t)pos * HEADS) = pal;
    bs[pos] = s;
}

// ---------------------------------------------------------------------------
// Gather. mac rows: one BLOCK per row. op rows: one WAVE per row.
// bf16 alpha, bf16 z gathers, wave LN + ELU.
// ---------------------------------------------------------------------------
__device__ __forceinline__ void seg2(const int* __restrict__ bs, const ushort_t* __restrict__ al,
                                     const ushort_t* __restrict__ zb,
                                     int s0, int e0, int stride, int lane, int hd, int col2,
                                     float& num0, float& num1, float& den) {
    for (int base = s0; base < e0; base += stride) {
        int nn = e0 - base;
        if (nn > 64) nn = 64;
        int sidx = 0;
        if (base + lane < e0) sidx = bs[base + lane];
#pragma unroll 8
        for (int i = 0; i < nn; ++i) {
            const int s = __shfl(sidx, i);
            const float a = __uint_as_float(((uint_t)al[(size_t)(base + i) * HEADS + hd]) << 16);
            const uint_t zz = *reinterpret_cast<const uint_t*>(zb + (size_t)s * OUT + col2);
            num0 = fmaf(a, __uint_as_float(zz << 16), num0);
            num1 = fmaf(a, __uint_as_float(zz & 0xffff0000u), num1);
            den += a;
        }
    }
}

__device__ __forceinline__ float2 ln_elu2(float x0, float x1, int lane,
                                          const float* __restrict__ g,
                                          const float* __restrict__ bb, int col2) {
    float s = x0 + x1;
#pragma unroll
    for (int m = 32; m >= 1; m >>= 1) s += __shfl_xor(s, m);
    const float mu = s * (1.0f / OUT);
    const float dx0 = x0 - mu, dx1 = x1 - mu;
    float q = dx0 * dx0 + dx1 * dx1;
#pragma unroll
    for (int m = 32; m >= 1; m >>= 1) q += __shfl_xor(q, m);
    const float r = rsqrtf(q * (1.0f / OUT) + LN_EPS);
    const float2 g2 = *reinterpret_cast<const float2*>(g + col2);
    const float2 b2 = *reinterpret_cast<const float2*>(bb + col2);
    float y0 = dx0 * r * g2.x + b2.x;
    float y1 = dx1 * r * g2.y + b2.y;
    y0 = (y0 > 0.f) ? y0 : expm1f(y0);
    y1 = (y1 > 0.f) ? y1 : expm1f(y1);
    return make_float2(y0, y1);
}

__global__ void k_gather(
    const int* __restrict__ bs_seq, const ushort_t* __restrict__ al_seq,
    const int* __restrict__ sta_seq, const int* __restrict__ off_seq,
    const int* __restrict__ bs_mo, const ushort_t* __restrict__ al_mo,
    const int* __restrict__ sta_mo, const int* __restrict__ off_mo,
    const int* __restrict__ bs_om, const ushort_t* __restrict__ al_om,
    const int* __restrict__ sta_om, const int* __restrict__ off_om,
    const ushort_t* __restrict__ zb_op, const ushort_t* __restrict__ zb_mac,
    const float* __restrict__ z_op, const float* __restrict__ z_mac,
    const float* __restrict__ g_op, const float* __restrict__ b_op,
    const float* __restrict__ g_mac, const float* __restrict__ b_mac,
    float* __restrict__ out_op, float* __restrict__ out_mac) {
    const int bid = blockIdx.x;
    const int t = threadIdx.x;
    const int w = t >> 6, lane = t & 63;
    const int hd = lane >> 4;
    const int col2 = lane * 2;
    __shared__ float nsh[4][OUT];
    __shared__ float dsh[4][HEADS];

    if (bid < N_MAC) {
        const int d = bid;
        const int s0 = sta_om[d], e0 = off_om[d];
        float num0 = 0.f, num1 = 0.f, den = 0.f;
        seg2(bs_om, al_om, zb_op, s0 + w * 64, e0, 256, lane, hd, col2, num0, num1, den);
        nsh[w][col2] = num0;
        nsh[w][col2 + 1] = num1;
        if ((lane & 15) == 0) dsh[w][hd] = den;
        __syncthreads();
        if (w == 0) {
            const float n0 = nsh[0][col2] + nsh[1][col2] + nsh[2][col2] + nsh[3][col2];
            const float n1 = nsh[0][col2 + 1] + nsh[1][col2 + 1] + nsh[2][col2 + 1] + nsh[3][col2 + 1];
            const float dt = dsh[0][hd] + dsh[1][hd] + dsh[2][hd] + dsh[3][hd];
            const float inv = 1.0f / (dt + EPS);
            const float2 zr = *reinterpret_cast<const float2*>(z_mac + (size_t)d * OUT + col2);
            const float2 o2 = ln_elu2(n0 * inv + zr.x, n1 * inv + zr.y, lane, g_mac, b_mac, col2);
            *reinterpret_cast<float2*>(out_mac + (size_t)d * OUT + col2) = o2;
        }
    } else {
        const int d = (bid - N_MAC) * 4 + w;
        if (d >= N_OP) return;
        float acc0 = 0.f, acc1 = 0.f;
        {
            float num0 = 0.f, num1 = 0.f, den = 0.f;
            seg2(bs_seq, al_seq, zb_op, sta_seq[d], off_seq[d], 64, lane, hd, col2, num0, num1, den);
            const float inv = 1.0f / (den + EPS);
            acc0 = num0 * inv; acc1 = num1 * inv;
        }
        {
            float num0 = 0.f, num1 = 0.f, den = 0.f;
            seg2(bs_mo, al_mo, zb_mac, sta_mo[d], off_mo[d], 64, lane, hd, col2, num0, num1, den);
            const float inv = 1.0f / (den + EPS);
            acc0 += num0 * inv; acc1 += num1 * inv;
        }
        const float2 zr = *reinterpret_cast<const float2*>(z_op + (size_t)d * OUT + col2);
        const float2 o2 = ln_elu2(acc0 + zr.x, acc1 + zr.y, lane, g_op, b_op, col2);
        *reinterpret_cast<float2*>(out_op + (size_t)d * OUT + col2) = o2;
    }
}

extern "C" void kernel_launch(void* const* d_in, const int* in_sizes, int n_in,
                              void* d_out, int out_size, void* d_ws, size_t ws_size,
                              hipStream_t stream) {
    const float* h_op      = (const float*)d_in[0];
    const float* h_mac     = (const float*)d_in[1];
    const int*   seq_src   = (const int*)d_in[2];
    const int*   seq_dst   = (const int*)d_in[3];
    const int*   om_src    = (const int*)d_in[4];
    const int*   om_dst    = (const int*)d_in[5];
    const int*   mo_src    = (const int*)d_in[6];
    const int*   mo_dst    = (const int*)d_in[7];
    const float* feat_seq  = (const float*)d_in[8];
    const float* feat_om   = (const float*)d_in[9];
    const float* feat_mo   = (const float*)d_in[10];
    const float* W_op_w    = (const float*)d_in[11];
    const float* W_op_b    = (const float*)d_in[12];
    const float* W_mac_w   = (const float*)d_in[13];
    const float* W_mac_b   = (const float*)d_in[14];
    const float* att_seq   = (const float*)d_in[15];
    const float* att_om    = (const float*)d_in[16];
    const float* att_mo    = (const float*)d_in[17];
    const float* ln_op_g   = (const float*)d_in[18];
    const float* ln_op_b   = (const float*)d_in[19];
    const float* ln_mac_g  = (const float*)d_in[20];
    const float* ln_mac_b  = (const float*)d_in[21];

    float* p = (float*)d_ws;
    float* z_op   = p; p += (size_t)N_OP * OUT;
    float* z_mac  = p; p += (size_t)N_MAC * OUT;
    float* p_op   = p; p += (size_t)N_OP * 16;
    float* p_mac  = p; p += (size_t)N_MAC * 8;
    ushort_t* al_seq = (ushort_t*)p; p += (size_t)E_SEQ * HEADS / 2;
    ushort_t* al_mo  = (ushort_t*)p; p += (size_t)E_MO * HEADS / 2;
    ushort_t* al_om  = (ushort_t*)p; p += (size_t)E_OM * HEADS / 2;
    float* c_op   = p; p += 16;
    float* c_mac  = p; p += 16;
    ushort_t* zb_op  = (ushort_t*)p; p += (size_t)N_OP * OUT / 2;
    ushort_t* zb_mac = (ushort_t*)p; p += (size_t)N_MAC * OUT / 2;
    ushort_t* hb_op  = (ushort_t*)p; p += (size_t)N_OP * IN_OP / 2;
    ushort_t* hb_mac = (ushort_t*)p; p += (size_t)N_MAC * IN_MAC / 2;
    ushort_t* Wb_op  = (ushort_t*)p; p += OUT * IN_OP / 2;
    ushort_t* Wb_mac = (ushort_t*)p; p += OUT * IN_MAC / 2;
    ushort_t* Ub_op  = (ushort_t*)p; p += 16 * IN_OP / 2;
    ushort_t* Ub_mac = (ushort_t*)p; p += 16 * IN_MAC / 2;
    int* q = (int*)p;
    int* cnt_seq = q; q += N_OP;    // cnt_* + ctr contiguous, zeroed in k_prep
    int* cnt_mo  = q; q += N_OP;
    int* cnt_om  = q; q += N_MAC;
    int* ctr     = q; q += 4;
    int* sta_seq = q; q += N_OP;
    int* sta_mo  = q; q += N_OP;
    int* sta_om  = q; q += N_MAC;
    int* off_seq = q; q += N_OP;
    int* off_mo  = q; q += N_OP;
    int* off_om  = q; q += N_MAC;
    int* bs_seq  = q; q += E_SEQ;
    int* bs_mo   = q; q += E_MO;
    int* bs_om   = q; q += E_OM;

    float* out_op  = (float*)d_out;
    float* out_mac = (float*)d_out + (size_t)N_OP * OUT;

    k_prep<<<256, 256, 0, stream>>>(W_op_w, W_op_b, W_mac_w, W_mac_b,
                                    att_seq, att_om, att_mo, h_op, h_mac,
                                    c_op, c_mac, Wb_op, Wb_mac, Ub_op, Ub_mac,
                                    hb_op, hb_mac, cnt_seq);

    k_gemm<<<GBA + GBB, 256, 0, stream>>>(
        hb_op, Wb_op, W_op_b, hb_mac, Wb_mac, W_mac_b,
        Ub_op, c_op, Ub_mac, c_mac,
        z_op, zb_op, z_mac, zb_mac, p_op, p_mac);

    k_histo<<<CNT_B, 256, 0, stream>>>(seq_dst, mo_dst, om_dst, cnt_seq, cnt_mo, cnt_om);

    k_alloc<<<AB_SEQ + AB_MO + AB_OM, 256, 0, stream>>>(
        cnt_seq, sta_seq, off_seq, cnt_mo, sta_mo, off_mo, cnt_om, sta_om, off_om, ctr);

    k_fill_alpha<<<CNT_B, 256, 0, stream>>>(
        seq_src, seq_dst, feat_seq, mo_src, mo_dst, feat_mo, om_src, om_dst, feat_om,
        p_op, p_mac, att_seq, att_mo, att_om,
        off_seq, off_mo, off_om,
        al_seq, al_mo, al_om, bs_seq, bs_mo, bs_om);

    k_gather<<<N_MAC + (N_OP + 3) / 4, 256, 0, stream>>>(
        bs_seq, al_seq, sta_seq, off_seq,
        bs_mo, al_mo, sta_mo, off_mo,
        bs_om, al_om, sta_om, off_om,
        zb_op, zb_mac, z_op, z_mac,
        ln_op_g, ln_op_b, ln_mac_g, ln_mac_b,
        out_op, out_mac);
}

// Round 11
// 191.076 us; speedup vs baseline: 2.1879x; 1.2376x over previous
//
#include <hip/hip_runtime.h>

#define N_OP   50000
#define N_MAC  2000
#define IN_OP  64
#define IN_MAC 32
#define OUT    128
#define HEADS  4
#define DK     32
#define ATT_DIM 65
#define E_SEQ  150000
#define E_OM   300000
#define E_MO   300000
#define TOT_E  (E_SEQ + E_MO + E_OM)
#define EPS    1e-6f
#define LN_EPS 1e-5f

#define TILES_OP  (N_OP / 16)            // 3125
#define TILES_MAC (N_MAC / 16)           // 125
#define GBA ((TILES_OP + 3) / 4)         // 782 blocks, 1 tile per wave
#define GBB ((TILES_MAC + 3) / 4)        // 32 blocks
#define CNT_B   ((TOT_E + 255) / 256)    // 2930

#define AB_SEQ  ((N_OP + 255) / 256)     // 196
#define AB_MO   ((N_OP + 255) / 256)     // 196
#define AB_OM   ((N_MAC + 255) / 256)    // 8
#define AB_TOT  (AB_SEQ + AB_MO + AB_OM) // 400

#define PREP_H  192                      // h-convert blocks in k_prep

typedef unsigned short ushort_t;
typedef unsigned int   uint_t;
typedef __attribute__((ext_vector_type(8))) short bf16x8;
typedef __attribute__((ext_vector_type(4))) float f32x4;

__device__ __forceinline__ ushort_t f32_to_bf16_rtne(float f) {
    uint_t u = __float_as_uint(f);
    u += 0x7FFFu + ((u >> 16) & 1u);
    return (ushort_t)(u >> 16);
}

// ---------------------------------------------------------------------------
// Prep (after memset of cnt/ctr). Regions:
//  b==0: fold attention through W (U bf16, c f32); convert W -> bf16.
//  b in [1, PREP_H]: convert h -> bf16 (grid-stride).
//  b >= PREP_H+1: histogram + RANK: rank_all[ge] = atomicAdd(&cnt[dst],1).
//  The rank makes fill atomic-free: pos = sta[dst] + rank.
// ---------------------------------------------------------------------------
__global__ void k_prep(const float* __restrict__ W_op, const float* __restrict__ b_op,
                       const float* __restrict__ W_mac, const float* __restrict__ b_mac,
                       const float* __restrict__ att_seq, const float* __restrict__ att_om,
                       const float* __restrict__ att_mo,
                       const float* __restrict__ h_op, const float* __restrict__ h_mac,
                       float* __restrict__ c_op, float* __restrict__ c_mac,
                       ushort_t* __restrict__ Wb_op, ushort_t* __restrict__ Wb_mac,
                       ushort_t* __restrict__ Ub_op, ushort_t* __restrict__ Ub_mac,
                       ushort_t* __restrict__ hb_op, ushort_t* __restrict__ hb_mac,
                       const int* __restrict__ seq_dst, const int* __restrict__ mo_dst,
                       const int* __restrict__ om_dst,
                       int* __restrict__ cnt_seq, int* __restrict__ cnt_mo,
                       int* __restrict__ cnt_om, int* __restrict__ rank_all) {
    const int t = threadIdx.x;
    const int b = blockIdx.x;
    if (b == 0) {
        for (int idx = t; idx < 16 * IN_OP; idx += 256) {
            const int j = idx >> 6, k = idx & 63;
            const int hd = j & 3, pr = j >> 2;
            const float* att = (pr <= 1) ? att_seq : (pr == 2 ? att_om : att_mo);
            const int off = (pr == 1 || pr == 3) ? 32 : 0;
            float s = 0.f;
            for (int l = 0; l < 32; ++l)
                s += att[hd * ATT_DIM + off + l] * W_op[(hd * 32 + l) * IN_OP + k];
            Ub_op[idx] = f32_to_bf16_rtne(s);
        }
        if (t < 16) {
            const int hd = t & 3, pr = t >> 2;
            const float* att = (pr <= 1) ? att_seq : (pr == 2 ? att_om : att_mo);
            const int off = (pr == 1 || pr == 3) ? 32 : 0;
            float s = 0.f;
            for (int l = 0; l < 32; ++l) s += att[hd * ATT_DIM + off + l] * b_op[hd * 32 + l];
            c_op[t] = s;
        }
        for (int idx = t; idx < 8 * IN_MAC; idx += 256) {
            const int j = idx >> 5, k = idx & 31;
            const int hd = j & 3, pr = j >> 2;
            const float* att = (pr == 0) ? att_om : att_mo;
            const int off = (pr == 0) ? 32 : 0;
            float s = 0.f;
            for (int l = 0; l < 32; ++l)
                s += att[hd * ATT_DIM + off + l] * W_mac[(hd * 32 + l) * IN_MAC + k];
            Ub_mac[idx] = f32_to_bf16_rtne(s);
        }
        for (int idx = 8 * IN_MAC + t; idx < 16 * IN_MAC; idx += 256) Ub_mac[idx] = 0;
        if (t < 8) {
            const int hd = t & 3, pr = t >> 2;
            const float* att = (pr == 0) ? att_om : att_mo;
            const int off = (pr == 0) ? 32 : 0;
            float s = 0.f;
            for (int l = 0; l < 32; ++l) s += att[hd * ATT_DIM + off + l] * b_mac[hd * 32 + l];
            c_mac[t] = s;
        }
        for (int idx = t; idx < OUT * IN_OP; idx += 256) Wb_op[idx] = f32_to_bf16_rtne(W_op[idx]);
        for (int idx = t; idx < OUT * IN_MAC; idx += 256) Wb_mac[idx] = f32_to_bf16_rtne(W_mac[idx]);
    } else if (b <= PREP_H) {
        const int base = (b - 1) * 256 + t;
        const int stride = PREP_H * 256;
        for (int i = base; i < N_OP * IN_OP; i += stride)
            hb_op[i] = f32_to_bf16_rtne(h_op[i]);
        for (int i = base; i < N_MAC * IN_MAC; i += stride)
            hb_mac[i] = f32_to_bf16_rtne(h_mac[i]);
    } else {
        const int ge = (b - PREP_H - 1) * 256 + t;
        if (ge < E_SEQ) rank_all[ge] = atomicAdd(&cnt_seq[seq_dst[ge]], 1);
        else if (ge < E_SEQ + E_MO) rank_all[ge] = atomicAdd(&cnt_mo[mo_dst[ge - E_SEQ]], 1);
        else if (ge < TOT_E) rank_all[ge] = atomicAdd(&cnt_om[om_dst[ge - E_SEQ - E_MO]], 1);
    }
}

// ---------------------------------------------------------------------------
// MFMA GEMM (+ fused range-allocation region).
//   A (h):  lane l -> row = row0+(l&15), k = (l>>4)*8 + j  (+32 for kstep 1)
//   B (W):  lane l -> col = ct*16+(l&15), same k mapping
//   C/D:    col = lane&15, row = (lane>>4)*4 + reg   [verified m89]
// Alloc region: per-wave scan of counts + one atomicAdd per wave on ctr;
// writes sta[] (segment start) and end[] (segment end).
// ---------------------------------------------------------------------------
__global__ void k_gemm(
    const ushort_t* __restrict__ hb_op, const ushort_t* __restrict__ Wb_op,
    const float* __restrict__ b_op,
    const ushort_t* __restrict__ hb_mac, const ushort_t* __restrict__ Wb_mac,
    const float* __restrict__ b_mac,
    const ushort_t* __restrict__ Ub_op, const float* __restrict__ c_op,
    const ushort_t* __restrict__ Ub_mac, const float* __restrict__ c_mac,
    float* __restrict__ z_op, ushort_t* __restrict__ zb_op,
    float* __restrict__ z_mac, ushort_t* __restrict__ zb_mac,
    float* __restrict__ p_op, float* __restrict__ p_mac,
    const int* __restrict__ cnt_seq, int* __restrict__ sta_seq, int* __restrict__ end_seq,
    const int* __restrict__ cnt_mo,  int* __restrict__ sta_mo,  int* __restrict__ end_mo,
    const int* __restrict__ cnt_om,  int* __restrict__ sta_om,  int* __restrict__ end_om,
    int* __restrict__ ctr) {
    const int bid = blockIdx.x;
    const int t = threadIdx.x;
    const int w = t >> 6, l = t & 63;
    const int li = l & 15, lg = l >> 4;

    if (bid < GBA) {
        const int tile = bid * 4 + w;
        if (tile >= TILES_OP) return;
        const int row0 = tile * 16;
        const bf16x8 a0 = *reinterpret_cast<const bf16x8*>(hb_op + (size_t)(row0 + li) * IN_OP + lg * 8);
        const bf16x8 a1 = *reinterpret_cast<const bf16x8*>(hb_op + (size_t)(row0 + li) * IN_OP + lg * 8 + 32);
        const int orow = row0 + lg * 4;
#pragma unroll
        for (int ct = 0; ct < 8; ++ct) {
            const int col = ct * 16 + li;
            const bf16x8 b0 = *reinterpret_cast<const bf16x8*>(Wb_op + (size_t)col * IN_OP + lg * 8);
            const bf16x8 b1 = *reinterpret_cast<const bf16x8*>(Wb_op + (size_t)col * IN_OP + lg * 8 + 32);
            f32x4 acc = {0.f, 0.f, 0.f, 0.f};
            acc = __builtin_amdgcn_mfma_f32_16x16x32_bf16(a0, b0, acc, 0, 0, 0);
            acc = __builtin_amdgcn_mfma_f32_16x16x32_bf16(a1, b1, acc, 0, 0, 0);
            const float bias = b_op[col];
#pragma unroll
            for (int r = 0; r < 4; ++r) {
                const float s = acc[r] + bias;
                const size_t o = (size_t)(orow + r) * OUT + col;
                z_op[o] = s;
                zb_op[o] = f32_to_bf16_rtne(s);
            }
        }
        {   // projection tile: p_op[row][j], j = lane&15
            const bf16x8 u0 = *reinterpret_cast<const bf16x8*>(Ub_op + (size_t)li * IN_OP + lg * 8);
            const bf16x8 u1 = *reinterpret_cast<const bf16x8*>(Ub_op + (size_t)li * IN_OP + lg * 8 + 32);
            f32x4 acc = {0.f, 0.f, 0.f, 0.f};
            acc = __builtin_amdgcn_mfma_f32_16x16x32_bf16(a0, u0, acc, 0, 0, 0);
            acc = __builtin_amdgcn_mfma_f32_16x16x32_bf16(a1, u1, acc, 0, 0, 0);
            const float cj = c_op[li];
#pragma unroll
            for (int r = 0; r < 4; ++r)
                p_op[(size_t)(orow + r) * 16 + li] = acc[r] + cj;
        }
    } else if (bid < GBA + GBB) {
        const int tile = (bid - GBA) * 4 + w;
        if (tile >= TILES_MAC) return;
        const int row0 = tile * 16;
        const bf16x8 a0 = *reinterpret_cast<const bf16x8*>(hb_mac + (size_t)(row0 + li) * IN_MAC + lg * 8);
        const int orow = row0 + lg * 4;
#pragma unroll
        for (int ct = 0; ct < 8; ++ct) {
            const int col = ct * 16 + li;
            const bf16x8 b0 = *reinterpret_cast<const bf16x8*>(Wb_mac + (size_t)col * IN_MAC + lg * 8);
            f32x4 acc = {0.f, 0.f, 0.f, 0.f};
            acc = __builtin_amdgcn_mfma_f32_16x16x32_bf16(a0, b0, acc, 0, 0, 0);
            const float bias = b_mac[col];
#pragma unroll
            for (int r = 0; r < 4; ++r) {
                const float s = acc[r] + bias;
                const size_t o = (size_t)(orow + r) * OUT + col;
                z_mac[o] = s;
                zb_mac[o] = f32_to_bf16_rtne(s);
            }
        }
        {
            const bf16x8 u0 = *reinterpret_cast<const bf16x8*>(Ub_mac + (size_t)li * IN_MAC + lg * 8);
            f32x4 acc = {0.f, 0.f, 0.f, 0.f};
            acc = __builtin_amdgcn_mfma_f32_16x16x32_bf16(a0, u0, acc, 0, 0, 0);
            if (li < 8) {
                const float cj = c_mac[li];
#pragma unroll
                for (int r = 0; r < 4; ++r)
                    p_mac[(size_t)(orow + r) * 8 + li] = acc[r] + cj;
            }
        }
    } else {
        // ---- alloc region ----
        const int b2 = bid - GBA - GBB;
        const int* cnt; int* sta; int* end; int n, g, lb;
        if (b2 < AB_SEQ)              { cnt = cnt_seq; sta = sta_seq; end = end_seq; n = N_OP;  g = 0; lb = b2; }
        else if (b2 < AB_SEQ + AB_MO) { cnt = cnt_mo;  sta = sta_mo;  end = end_mo;  n = N_OP;  g = 1; lb = b2 - AB_SEQ; }
        else                          { cnt = cnt_om;  sta = sta_om;  end = end_om;  n = N_MAC; g = 2; lb = b2 - AB_SEQ - AB_MO; }
        const int d = lb * 256 + t;
        const int lane = l;
        const int v = (d < n) ? cnt[d] : 0;
        int x = v;
#pragma unroll
        for (int m = 1; m < 64; m <<= 1) {
            int y = __shfl_up(x, m);
            if (lane >= m) x += y;
        }
        int base = 0;
        if (lane == 63) base = atomicAdd(&ctr[g], x);
        base = __shfl(base, 63);
        if (d < n) {
            sta[d] = base + x - v;
            end[d] = base + x;
        }
    }
}

// ---------------------------------------------------------------------------
// Fill: NO atomics (pos = sta[dst] + rank from prep). One 16B record per
// edge: {src, al01, al23, 0} (single scattered store -> 1 line-touch/edge).
// ---------------------------------------------------------------------------
__global__ void k_fill(
    const int* __restrict__ seq_src, const int* __restrict__ seq_dst, const float* __restrict__ feat_seq,
    const int* __restrict__ mo_src,  const int* __restrict__ mo_dst,  const float* __restrict__ feat_mo,
    const int* __restrict__ om_src,  const int* __restrict__ om_dst,  const float* __restrict__ feat_om,
    const float* __restrict__ p_op, const float* __restrict__ p_mac,
    const float* __restrict__ att_seq, const float* __restrict__ att_mo, const float* __restrict__ att_om,
    const int* __restrict__ sta_seq, const int* __restrict__ sta_mo, const int* __restrict__ sta_om,
    const int* __restrict__ rank_all,
    uint4* __restrict__ rec_seq, uint4* __restrict__ rec_mo, uint4* __restrict__ rec_om) {
    const int ge = blockIdx.x * 256 + threadIdx.x;
    if (ge >= TOT_E) return;
    int s, d, pos;
    float f;
    float4 as, ad, aw;
    uint4* rec;
    if (ge < E_SEQ) {
        const int e = ge;
        s = seq_src[e]; d = seq_dst[e]; f = feat_seq[e];
        as = *reinterpret_cast<const float4*>(p_op + (size_t)s * 16 + 0);
        ad = *reinterpret_cast<const float4*>(p_op + (size_t)d * 16 + 4);
        aw = make_float4(att_seq[64], att_seq[ATT_DIM + 64], att_seq[2 * ATT_DIM + 64], att_seq[3 * ATT_DIM + 64]);
        pos = sta_seq[d] + rank_all[ge];
        rec = rec_seq;
    } else if (ge < E_SEQ + E_MO) {
        const int e = ge - E_SEQ;
        s = mo_src[e]; d = mo_dst[e]; f = feat_mo[e];
        as = *reinterpret_cast<const float4*>(p_mac + (size_t)s * 8 + 4);
        ad = *reinterpret_cast<const float4*>(p_op + (size_t)d * 16 + 12);
        aw = make_float4(att_mo[64], att_mo[ATT_DIM + 64], att_mo[2 * ATT_DIM + 64], att_mo[3 * ATT_DIM + 64]);
        pos = sta_mo[d] + rank_all[ge];
        rec = rec_mo;
    } else {
        const int e = ge - E_SEQ - E_MO;
        s = om_src[e]; d = om_dst[e]; f = feat_om[e];
        as = *reinterpret_cast<const float4*>(p_op + (size_t)s * 16 + 8);
        ad = *reinterpret_cast<const float4*>(p_mac + (size_t)d * 8 + 0);
        aw = make_float4(att_om[64], att_om[ATT_DIM + 64], att_om[2 * ATT_DIM + 64], att_om[3 * ATT_DIM + 64]);
        pos = sta_om[d] + rank_all[ge];
        rec = rec_om;
    }
    const float sc[4] = {as.x + ad.x + f * aw.x, as.y + ad.y + f * aw.y,
                         as.z + ad.z + f * aw.z, as.w + ad.w + f * aw.w};
    uint_t b16[4];
#pragma unroll
    for (int hh = 0; hh < 4; ++hh) {
        float v = sc[hh];
        v = (v >= 0.f) ? v : 0.2f * v;
        v = fminf(fmaxf(v, -20.f), 20.f);
        b16[hh] = f32_to_bf16_rtne(expf(v));
    }
    uint4 r;
    r.x = (uint_t)s;
    r.y = b16[0] | (b16[1] << 16);
    r.z = b16[2] | (b16[3] << 16);
    r.w = 0;
    rec[pos] = r;
}

// ---------------------------------------------------------------------------
// Gather. Records carry src+alpha; per-edge alpha comes from shfl of the
// staged record (no per-edge VMEM). mac rows: one BLOCK per row; op rows:
// one WAVE per row. bf16 z gathers, wave LN + ELU.
// ---------------------------------------------------------------------------
__device__ __forceinline__ void seg2(const uint4* __restrict__ rec,
                                     const ushort_t* __restrict__ zb,
                                     int s0, int e0, int stride, int lane, int hd, int col2,
                                     float& num0, float& num1, float& den) {
    const uint_t hiSel = hd & 1;          // 0: low half, 1: high half
    const uint_t wSel = hd >> 1;          // 0: word y, 1: word z
    for (int base = s0; base < e0; base += stride) {
        int nn = e0 - base;
        if (nn > 64) nn = 64;
        uint4 r = {0u, 0u, 0u, 0u};
        if (base + lane < e0) r = rec[base + lane];
#pragma unroll 8
        for (int i = 0; i < nn; ++i) {
            const int s = __shfl((int)r.x, i);
            const uint_t wy = (uint_t)__shfl((int)r.y, i);
            const uint_t wz = (uint_t)__shfl((int)r.z, i);
            const uint_t pick = wSel ? wz : wy;
            const float a = __uint_as_float(hiSel ? (pick & 0xffff0000u) : (pick << 16));
            const uint_t zz = *reinterpret_cast<const uint_t*>(zb + (size_t)s * OUT + col2);
            num0 = fmaf(a, __uint_as_float(zz << 16), num0);
            num1 = fmaf(a, __uint_as_float(zz & 0xffff0000u), num1);
            den += a;
        }
    }
}

__device__ __forceinline__ float2 ln_elu2(float x0, float x1, int lane,
                                          const float* __restrict__ g,
                                          const float* __restrict__ bb, int col2) {
    float s = x0 + x1;
#pragma unroll
    for (int m = 32; m >= 1; m >>= 1) s += __shfl_xor(s, m);
    const float mu = s * (1.0f / OUT);
    const float dx0 = x0 - mu, dx1 = x1 - mu;
    float q = dx0 * dx0 + dx1 * dx1;
#pragma unroll
    for (int m = 32; m >= 1; m >>= 1) q += __shfl_xor(q, m);
    const float r = rsqrtf(q * (1.0f / OUT) + LN_EPS);
    const float2 g2 = *reinterpret_cast<const float2*>(g + col2);
    const float2 b2 = *reinterpret_cast<const float2*>(bb + col2);
    float y0 = dx0 * r * g2.x + b2.x;
    float y1 = dx1 * r * g2.y + b2.y;
    y0 = (y0 > 0.f) ? y0 : expm1f(y0);
    y1 = (y1 > 0.f) ? y1 : expm1f(y1);
    return make_float2(y0, y1);
}

__global__ void k_gather(
    const uint4* __restrict__ rec_seq, const int* __restrict__ sta_seq, const int* __restrict__ end_seq,
    const uint4* __restrict__ rec_mo,  const int* __restrict__ sta_mo,  const int* __restrict__ end_mo,
    const uint4* __restrict__ rec_om,  const int* __restrict__ sta_om,  const int* __restrict__ end_om,
    const ushort_t* __restrict__ zb_op, const ushort_t* __restrict__ zb_mac,
    const float* __restrict__ z_op, const float* __restrict__ z_mac,
    const float* __restrict__ g_op, const float* __restrict__ b_op,
    const float* __restrict__ g_mac, const float* __restrict__ b_mac,
    float* __restrict__ out_op, float* __restrict__ out_mac) {
    const int bid = blockIdx.x;
    const int t = threadIdx.x;
    const int w = t >> 6, lane = t & 63;
    const int hd = lane >> 4;
    const int col2 = lane * 2;
    __shared__ float nsh[4][OUT];
    __shared__ float dsh[4][HEADS];

    if (bid < N_MAC) {
        const int d = bid;
        const int s0 = sta_om[d], e0 = end_om[d];
        float num0 = 0.f, num1 = 0.f, den = 0.f;
        seg2(rec_om, zb_op, s0 + w * 64, e0, 256, lane, hd, col2, num0, num1, den);
        nsh[w][col2] = num0;
        nsh[w][col2 + 1] = num1;
        if ((lane & 15) == 0) dsh[w][hd] = den;
        __syncthreads();
        if (w == 0) {
            const float n0 = nsh[0][col2] + nsh[1][col2] + nsh[2][col2] + nsh[3][col2];
            const float n1 = nsh[0][col2 + 1] + nsh[1][col2 + 1] + nsh[2][col2 + 1] + nsh[3][col2 + 1];
            const float dt = dsh[0][hd] + dsh[1][hd] + dsh[2][hd] + dsh[3][hd];
            const float inv = 1.0f / (dt + EPS);
            const float2 zr = *reinterpret_cast<const float2*>(z_mac + (size_t)d * OUT + col2);
            const float2 o2 = ln_elu2(n0 * inv + zr.x, n1 * inv + zr.y, lane, g_mac, b_mac, col2);
            *reinterpret_cast<float2*>(out_mac + (size_t)d * OUT + col2) = o2;
        }
    } else {
        const int d = (bid - N_MAC) * 4 + w;
        if (d >= N_OP) return;
        float acc0 = 0.f, acc1 = 0.f;
        {
            float num0 = 0.f, num1 = 0.f, den = 0.f;
            seg2(rec_seq, zb_op, sta_seq[d], end_seq[d], 64, lane, hd, col2, num0, num1, den);
            const float inv = 1.0f / (den + EPS);
            acc0 = num0 * inv; acc1 = num1 * inv;
        }
        {
            float num0 = 0.f, num1 = 0.f, den = 0.f;
            seg2(rec_mo, zb_mac, sta_mo[d], end_mo[d], 64, lane, hd, col2, num0, num1, den);
            const float inv = 1.0f / (den + EPS);
            acc0 += num0 * inv; acc1 += num1 * inv;
        }
        const float2 zr = *reinterpret_cast<const float2*>(z_op + (size_t)d * OUT + col2);
        const float2 o2 = ln_elu2(acc0 + zr.x, acc1 + zr.y, lane, g_op, b_op, col2);
        *reinterpret_cast<float2*>(out_op + (size_t)d * OUT + col2) = o2;
    }
}

extern "C" void kernel_launch(void* const* d_in, const int* in_sizes, int n_in,
                              void* d_out, int out_size, void* d_ws, size_t ws_size,
                              hipStream_t stream) {
    const float* h_op      = (const float*)d_in[0];
    const float* h_mac     = (const float*)d_in[1];
    const int*   seq_src   = (const int*)d_in[2];
    const int*   seq_dst   = (const int*)d_in[3];
    const int*   om_src    = (const int*)d_in[4];
    const int*   om_dst    = (const int*)d_in[5];
    const int*   mo_src    = (const int*)d_in[6];
    const int*   mo_dst    = (const int*)d_in[7];
    const float* feat_seq  = (const float*)d_in[8];
    const float* feat_om   = (const float*)d_in[9];
    const float* feat_mo   = (const float*)d_in[10];
    const float* W_op_w    = (const float*)d_in[11];
    const float* W_op_b    = (const float*)d_in[12];
    const float* W_mac_w   = (const float*)d_in[13];
    const float* W_mac_b   = (const float*)d_in[14];
    const float* att_seq   = (const float*)d_in[15];
    const float* att_om    = (const float*)d_in[16];
    const float* att_mo    = (const float*)d_in[17];
    const float* ln_op_g   = (const float*)d_in[18];
    const float* ln_op_b   = (const float*)d_in[19];
    const float* ln_mac_g  = (const float*)d_in[20];
    const float* ln_mac_b  = (const float*)d_in[21];

    float* p = (float*)d_ws;
    float* z_op   = p; p += (size_t)N_OP * OUT;
    float* z_mac  = p; p += (size_t)N_MAC * OUT;
    float* p_op   = p; p += (size_t)N_OP * 16;
    float* p_mac  = p; p += (size_t)N_MAC * 8;
    float* c_op   = p; p += 16;
    float* c_mac  = p; p += 16;
    uint4* rec_seq = (uint4*)p; p += (size_t)E_SEQ * 4;
    uint4* rec_mo  = (uint4*)p; p += (size_t)E_MO * 4;
    uint4* rec_om  = (uint4*)p; p += (size_t)E_OM * 4;
    ushort_t* zb_op  = (ushort_t*)p; p += (size_t)N_OP * OUT / 2;
    ushort_t* zb_mac = (ushort_t*)p; p += (size_t)N_MAC * OUT / 2;
    ushort_t* hb_op  = (ushort_t*)p; p += (size_t)N_OP * IN_OP / 2;
    ushort_t* hb_mac = (ushort_t*)p; p += (size_t)N_MAC * IN_MAC / 2;
    ushort_t* Wb_op  = (ushort_t*)p; p += OUT * IN_OP / 2;
    ushort_t* Wb_mac = (ushort_t*)p; p += OUT * IN_MAC / 2;
    ushort_t* Ub_op  = (ushort_t*)p; p += 16 * IN_OP / 2;
    ushort_t* Ub_mac = (ushort_t*)p; p += 16 * IN_MAC / 2;
    int* q = (int*)p;
    int* cnt_seq = q; q += N_OP;    // cnt_* + ctr contiguous -> one memset
    int* cnt_mo  = q; q += N_OP;
    int* cnt_om  = q; q += N_MAC;
    int* ctr     = q; q += 4;
    int* sta_seq = q; q += N_OP;
    int* sta_mo  = q; q += N_OP;
    int* sta_om  = q; q += N_MAC;
    int* end_seq = q; q += N_OP;
    int* end_mo  = q; q += N_OP;
    int* end_om  = q; q += N_MAC;
    int* rank_all = q; q += TOT_E;

    float* out_op  = (float*)d_out;
    float* out_mac = (float*)d_out + (size_t)N_OP * OUT;

    hipMemsetAsync(cnt_seq, 0, (size_t)(2 * N_OP + N_MAC + 4) * sizeof(int), stream);

    k_prep<<<1 + PREP_H + CNT_B, 256, 0, stream>>>(
        W_op_w, W_op_b, W_mac_w, W_mac_b,
        att_seq, att_om, att_mo, h_op, h_mac,
        c_op, c_mac, Wb_op, Wb_mac, Ub_op, Ub_mac,
        hb_op, hb_mac,
        seq_dst, mo_dst, om_dst, cnt_seq, cnt_mo, cnt_om, rank_all);

    k_gemm<<<GBA + GBB + AB_TOT, 256, 0, stream>>>(
        hb_op, Wb_op, W_op_b, hb_mac, Wb_mac, W_mac_b,
        Ub_op, c_op, Ub_mac, c_mac,
        z_op, zb_op, z_mac, zb_mac, p_op, p_mac,
        cnt_seq, sta_seq, end_seq, cnt_mo, sta_mo, end_mo, cnt_om, sta_om, end_om, ctr);

    k_fill<<<CNT_B, 256, 0, stream>>>(
        seq_src, seq_dst, feat_seq, mo_src, mo_dst, feat_mo, om_src, om_dst, feat_om,
        p_op, p_mac, att_seq, att_mo, att_om,
        sta_seq, sta_mo, sta_om, rank_all,
        rec_seq, rec_mo, rec_om);

    k_gather<<<N_MAC + (N_OP + 3) / 4, 256, 0, stream>>>(
        rec_seq, sta_seq, end_seq,
        rec_mo, sta_mo, end_mo,
        rec_om, sta_om, end_om,
        zb_op, zb_mac, z_op, z_mac,
        ln_op_g, ln_op_b, ln_mac_g, ln_mac_b,
        out_op, out_mac);
}